// Round 9
// baseline (296.995 us; speedup 1.0000x reference)
//
#include <hip/hip_runtime.h>
#include <utility>

// Problem constants: N=262144 rows, NX=NQ=64, NU=16, fp32.
#define NROWS 262144
#define BT 512                 // threads/block (8 waves; 4 blocks/CU)
#define RPB 256                // rows/block (= BT/4 quads * 2 rows each)

typedef float f16v __attribute__((ext_vector_type(16)));
typedef float f4v  __attribute__((ext_vector_type(4)));

// d_ws layout (floats) — two contiguous 9280-float phase blocks:
//  phase1 @0    : C1T[4096] | D11T[4096] | D12T[1024] | bv[64]
//  phase2 @9280 : AT [4096] | B1T [4096] | B2T [1024] | bx[64]
//  C1T[j*64+i]=C1[i][j]  D11T[i*64+k]=D11[k][i] (zeros at k<=i come from input)
//  D12T[j*64+i]=D12[i][j]  AT[j*64+k]=A[k][j]  B1T[i*64+k]=B1[k][i]
//  B2T[j*64+k]=B2[k][j]
// The fused kernel stages ONE 37.12 KB phase block at a time (overlay):
// 37.12 KB -> 4 blocks/CU -> 32 waves/CU (round 7's 74 KB capped at 16).

__global__ void prep_kernel(const float* __restrict__ A, const float* __restrict__ B1,
                            const float* __restrict__ B2, const float* __restrict__ C1,
                            const float* __restrict__ D11, const float* __restrict__ D12,
                            const float* __restrict__ bv, const float* __restrict__ bx,
                            float* __restrict__ ws) {
    int g = blockIdx.x * 256 + threadIdx.x;
    if (g < 4096) {
        int r = g >> 6, c = g & 63;       // source row r, col c (64x64 row-major)
        int to = c * 64 + r;
        ws[0     + to] = C1[g];           // C1T
        ws[4096  + to] = D11[g];          // D11T
        ws[9280  + to] = A[g];            // AT
        ws[13376 + to] = B1[g];           // B1T
    }
    if (g < 1024) {
        int r = g >> 4, c = g & 15;       // 64x16 row-major source
        int to = c * 64 + r;
        ws[8192  + to] = D12[g];          // D12T
        ws[17472 + to] = B2[g];           // B2T
    }
    if (g < 64) {
        ws[9216  + g] = bv[g];
        ws[18496 + g] = bx[g];
    }
}

__device__ __forceinline__ f16v lds16(const float* p) { return *(const f16v*)p; }

// Pin pass boundaries: stops the scheduler from hoisting next-pass LDS
// chunks / extending fragment live ranges across passes. Compile-time only.
__device__ __forceinline__ void fence_sched() { __builtin_amdgcn_sched_barrier(0); }

// Quad-lane broadcast via DPP quad_perm:[Q,Q,Q,Q] — pure VALU (~2 cyc).
template<int Q>
__device__ __forceinline__ float qbcast(float v) {
    return __int_as_float(__builtin_amdgcn_update_dpp(
        0, __float_as_int(v), Q * 0x55, 0xF, 0xF, true));
}

// R=2 register blocking: one LDS matrix chunk feeds BOTH rows' FMAs.
// Register discipline (rounds 4-7): fragment baseline stays ~72 regs in
// every pass (x/u are RE-READ from global after the substitution) -> body
// fits 64 VGPRs = the cap for 8 waves/SIMD, enforced by launch_bounds.

// Substitution step I for two independent rows sharing the D11T column.
template<int I>
__device__ __forceinline__ void substep2(f16v& s0, f16v& s1, const float* D11s,
                                         int c16, int c) {
    const float w0 = fmaxf(qbcast<(I >> 4)>(s0[I & 15]), 0.0f);
    const float w1 = fmaxf(qbcast<(I >> 4)>(s1[I & 15]), 0.0f);
    const f16v m = lds16(D11s + I * 64 + c16);     // D11T[I][I]==0, owner-safe
    s0 += m * w0;
    s1 += m * w1;
    s0[I & 15] = (c == (I >> 4)) ? w0 : s0[I & 15];  // owner finalizes
    s1[I & 15] = (c == (I >> 4)) ? w1 : s1[I & 15];
}
template<int... Is>
__device__ __forceinline__ void subst_all2(f16v& s0, f16v& s1, const float* D11s,
                                           int c16, int c,
                                           std::integer_sequence<int, Is...>) {
    (substep2<Is>(s0, s1, D11s, c16, c), ...);
}

// 64-dim matvec, two rows: multiplier scalars live quad-distributed
// (16/lane/row) and are DPP-broadcast; matrix chunk loaded once.
template<int J>
__device__ __forceinline__ void mv64step2(f16v& a0, f16v& a1, const float* Ms,
                                          int c16, const f16v& f0, const f16v& f1) {
    const f16v m = lds16(Ms + J * 64 + c16);
    a0 += m * qbcast<(J >> 4)>(f0[J & 15]);
    a1 += m * qbcast<(J >> 4)>(f1[J & 15]);
}
template<int... Js>
__device__ __forceinline__ void mv64_2(f16v& a0, f16v& a1, const float* Ms, int c16,
                                       const f16v& f0, const f16v& f1,
                                       std::integer_sequence<int, Js...>) {
    (mv64step2<Js>(a0, a1, Ms, c16, f0, f1), ...);
}

// 16-dim matvec, two rows (u fragments: 4 scalars/lane/row).
template<int J>
__device__ __forceinline__ void mv16step2(f16v& a0, f16v& a1, const float* Ms,
                                          int c16, const f4v& f0, const f4v& f1) {
    const f16v m = lds16(Ms + J * 64 + c16);
    a0 += m * qbcast<(J >> 2)>(f0[J & 3]);
    a1 += m * qbcast<(J >> 2)>(f1[J & 3]);
}
template<int... Js>
__device__ __forceinline__ void mv16_2(f16v& a0, f16v& a1, const float* Ms, int c16,
                                       const f4v& f0, const f4v& f1,
                                       std::integer_sequence<int, Js...>) {
    (mv16step2<Js>(a0, a1, Ms, c16, f0, f1), ...);
}

// Fused kernel: quad (4 lanes) per TWO rows (row q and row q+128); each lane
// owns a 16-output chunk of each. ONE phase table LDS-resident at a time
// (overlay mid-kernel): 37.12 KB -> 4 blocks/CU = 32 waves/CU, 4 independent
// 8-wave barrier domains (round 8 showed fused big domains hurt).
// Pass order caps fragment liveness (round-7-proven 64-VGPR schedule):
//   stage p1; 1. s = bv + C1 x + D12 u  [xf, uf die]
//   2. substitution s -> w
//   overlay p2 (live: s only)
//   3. acc = bx + B1 w                  [s dies]
//   4. reload x,u; acc += Ax + B2u
__global__ __launch_bounds__(BT, 8) void renl2_fused(const float* __restrict__ x,
                                                     const float* __restrict__ u,
                                                     const float* __restrict__ ws,
                                                     float* __restrict__ out) {
    __shared__ __align__(64) float sm[9280];    // 37.12 KB -> 4 blocks/CU
    const int tid = threadIdx.x;
    const int c   = tid & 3;              // quad chunk id
    const int c16 = c << 4;
    const size_t row0 = (size_t)blockIdx.x * RPB;   // rows [row0, row0+256)

    // ---- per-lane x/u fragments for both rows (fully coalesced) ----
    const f16v xf0 = *(const f16v*)(x + row0 * 64 + (size_t)tid * 16);
    const f16v xf1 = *(const f16v*)(x + (row0 + 128) * 64 + (size_t)tid * 16);
    const f4v  uf0 = *(const f4v*) (u + row0 * 16 + (size_t)tid * 4);
    const f4v  uf1 = *(const f4v*) (u + (row0 + 128) * 16 + (size_t)tid * 4);

    // ---- stage phase-1 table (2320 float4) ----
    const float4* wsv = (const float4*)ws;
    float4* smv = (float4*)sm;
#pragma unroll
    for (int i = 0; i < 4; i++) smv[tid + i * BT] = wsv[tid + i * BT];
    if (tid < 2320 - 4 * BT) smv[tid + 4 * BT] = wsv[tid + 4 * BT];
    __syncthreads();

    // ---- pass 1: s = bv + C1 x + D12 u   (xf, uf die here) ----
    f16v s0 = lds16(sm + 9216 + c16);
    f16v s1 = s0;
    mv64_2(s0, s1, sm + 0,    c16, xf0, xf1, std::make_integer_sequence<int, 64>{});
    mv16_2(s0, s1, sm + 8192, c16, uf0, uf1, std::make_integer_sequence<int, 16>{});
    fence_sched();

    // ---- pass 2: substitution (intra-quad DPP broadcast, branchless) ----
    subst_all2(s0, s1, sm + 4096, c16, c, std::make_integer_sequence<int, 64>{});
    fence_sched();

    // ---- overlay: phase-2 table (live regs: s0,s1 only) ----
    __syncthreads();
#pragma unroll
    for (int i = 0; i < 4; i++) smv[tid + i * BT] = wsv[2320 + tid + i * BT];
    if (tid < 2320 - 4 * BT) smv[tid + 4 * BT] = wsv[2320 + tid + 4 * BT];
    __syncthreads();
    // local layout now: AT@0 | B1T@4096 | B2T@8192 | bx@9216

    // ---- pass 3: acc = bx + B1 w   (s dies here) ----
    f16v acc0 = lds16(sm + 9216 + c16);
    f16v acc1 = acc0;
    mv64_2(acc0, acc1, sm + 4096, c16, s0, s1, std::make_integer_sequence<int, 64>{});
    fence_sched();

    // ---- pass 4: reload x/u (L3-hot; pointer laundered so the compiler
    //      cannot CSE-forward the pass-1 loads and resurrect their ranges),
    //      then acc += A x + B2 u ----
    size_t r0 = row0;
    asm volatile("" : "+s"(r0));          // opaque: forces a true reload
    const f16v xg0 = *(const f16v*)(x + r0 * 64 + (size_t)tid * 16);
    const f16v xg1 = *(const f16v*)(x + (r0 + 128) * 64 + (size_t)tid * 16);
    const f4v  ug0 = *(const f4v*) (u + r0 * 16 + (size_t)tid * 4);
    const f4v  ug1 = *(const f4v*) (u + (r0 + 128) * 16 + (size_t)tid * 4);
    mv64_2(acc0, acc1, sm + 0,    c16, xg0, xg1, std::make_integer_sequence<int, 64>{});
    mv16_2(acc0, acc1, sm + 8192, c16, ug0, ug1, std::make_integer_sequence<int, 16>{});

    // ---- two 64B stores: x_dot for both rows ----
    const size_t q = (size_t)(tid >> 2);
    *(f16v*)(out + (row0 + q) * 64 + c16)       = acc0;
    *(f16v*)(out + (row0 + 128 + q) * 64 + c16) = acc1;
}

extern "C" void kernel_launch(void* const* d_in, const int* in_sizes, int n_in,
                              void* d_out, int out_size, void* d_ws, size_t ws_size,
                              hipStream_t stream) {
    const float* x   = (const float*)d_in[0];
    const float* u   = (const float*)d_in[1];
    const float* A   = (const float*)d_in[2];
    const float* B1  = (const float*)d_in[3];
    const float* B2  = (const float*)d_in[4];
    const float* C1  = (const float*)d_in[5];
    const float* D11 = (const float*)d_in[6];
    const float* D12 = (const float*)d_in[7];
    const float* bv  = (const float*)d_in[8];
    const float* bx  = (const float*)d_in[9];
    float* out = (float*)d_out;
    float* ws  = (float*)d_ws;

    prep_kernel<<<16, 256, 0, stream>>>(A, B1, B2, C1, D11, D12, bv, bx, ws);
    renl2_fused<<<NROWS / RPB, BT, 0, stream>>>(x, u, ws, out);
}

// Round 10
// 241.425 us; speedup vs baseline: 1.2302x; 1.2302x over previous
//
#include <hip/hip_runtime.h>
#include <utility>

// Problem constants: N=262144 rows, NX=NQ=64, NU=16, fp32.
#define NROWS 262144
#define BT 512                 // threads/block (8 waves)
#define RPB 256                // rows/block (= BT/4 quads * 2 rows each)

typedef float f16v __attribute__((ext_vector_type(16)));
typedef float f4v  __attribute__((ext_vector_type(4)));

// d_ws layout (floats) — two contiguous 9280-float phase blocks:
//  phase1 @0    : C1T[4096] | D11T[4096] | D12T[1024] | bv[64]
//  phase2 @9280 : AT [4096] | B1T [4096] | B2T [1024] | bx[64]
//  C1T[j*64+i]=C1[i][j]  D11T[i*64+k]=D11[k][i] (zeros at k<=i come from input)
//  D12T[j*64+i]=D12[i][j]  AT[j*64+k]=A[k][j]  B1T[i*64+k]=B1[k][i]
//  B2T[j*64+k]=B2[k][j]
// The fused kernel stages ONE 37.12 KB phase block at a time (overlay):
// 37.12 KB -> 4 blocks/CU -> 32 waves/CU.

__global__ void prep_kernel(const float* __restrict__ A, const float* __restrict__ B1,
                            const float* __restrict__ B2, const float* __restrict__ C1,
                            const float* __restrict__ D11, const float* __restrict__ D12,
                            const float* __restrict__ bv, const float* __restrict__ bx,
                            float* __restrict__ ws) {
    int g = blockIdx.x * 256 + threadIdx.x;
    if (g < 4096) {
        int r = g >> 6, c = g & 63;       // source row r, col c (64x64 row-major)
        int to = c * 64 + r;
        ws[0     + to] = C1[g];           // C1T
        ws[4096  + to] = D11[g];          // D11T
        ws[9280  + to] = A[g];            // AT
        ws[13376 + to] = B1[g];           // B1T
    }
    if (g < 1024) {
        int r = g >> 4, c = g & 15;       // 64x16 row-major source
        int to = c * 64 + r;
        ws[8192  + to] = D12[g];          // D12T
        ws[17472 + to] = B2[g];           // B2T
    }
    if (g < 64) {
        ws[9216  + g] = bv[g];
        ws[18496 + g] = bx[g];
    }
}

__device__ __forceinline__ f16v lds16(const float* p) { return *(const f16v*)p; }

// Pin pass boundaries: stops the scheduler from hoisting next-pass LDS
// chunks / extending fragment live ranges across passes. Compile-time only.
__device__ __forceinline__ void fence_sched() { __builtin_amdgcn_sched_barrier(0); }

// Quad-lane broadcast via DPP quad_perm:[Q,Q,Q,Q] — pure VALU (~2 cyc).
template<int Q>
__device__ __forceinline__ float qbcast(float v) {
    return __int_as_float(__builtin_amdgcn_update_dpp(
        0, __float_as_int(v), Q * 0x55, 0xF, 0xF, true));
}

// R=2 register blocking: one LDS matrix chunk feeds BOTH rows' FMAs.
// Register discipline (rounds 4-7): fragment baseline stays ~72 regs in
// every pass (x/u are RE-READ from global after the substitution) -> body
// fits 64 VGPRs (round 7 proved it: chose 64 voluntarily under a 128 cap).
// launch_bounds 2nd arg semantics (measured r0-r9): hipcc treats it as
// MIN WORKGROUPS/CU (CUDA-style): VGPR cap = 512/(2*arg) at BT=512.
// arg=4 -> 4 blocks/CU = 32 waves/CU (HW max), cap 64. arg=8 (r9) forced
// cap 32 -> catastrophic spill. arg=2 (r7) capped occupancy at 16 waves/CU.

// Substitution step I for two independent rows sharing the D11T column.
template<int I>
__device__ __forceinline__ void substep2(f16v& s0, f16v& s1, const float* D11s,
                                         int c16, int c) {
    const float w0 = fmaxf(qbcast<(I >> 4)>(s0[I & 15]), 0.0f);
    const float w1 = fmaxf(qbcast<(I >> 4)>(s1[I & 15]), 0.0f);
    const f16v m = lds16(D11s + I * 64 + c16);     // D11T[I][I]==0, owner-safe
    s0 += m * w0;
    s1 += m * w1;
    s0[I & 15] = (c == (I >> 4)) ? w0 : s0[I & 15];  // owner finalizes
    s1[I & 15] = (c == (I >> 4)) ? w1 : s1[I & 15];
}
template<int... Is>
__device__ __forceinline__ void subst_all2(f16v& s0, f16v& s1, const float* D11s,
                                           int c16, int c,
                                           std::integer_sequence<int, Is...>) {
    (substep2<Is>(s0, s1, D11s, c16, c), ...);
}

// 64-dim matvec, two rows: multiplier scalars live quad-distributed
// (16/lane/row) and are DPP-broadcast; matrix chunk loaded once.
template<int J>
__device__ __forceinline__ void mv64step2(f16v& a0, f16v& a1, const float* Ms,
                                          int c16, const f16v& f0, const f16v& f1) {
    const f16v m = lds16(Ms + J * 64 + c16);
    a0 += m * qbcast<(J >> 4)>(f0[J & 15]);
    a1 += m * qbcast<(J >> 4)>(f1[J & 15]);
}
template<int... Js>
__device__ __forceinline__ void mv64_2(f16v& a0, f16v& a1, const float* Ms, int c16,
                                       const f16v& f0, const f16v& f1,
                                       std::integer_sequence<int, Js...>) {
    (mv64step2<Js>(a0, a1, Ms, c16, f0, f1), ...);
}

// 16-dim matvec, two rows (u fragments: 4 scalars/lane/row).
template<int J>
__device__ __forceinline__ void mv16step2(f16v& a0, f16v& a1, const float* Ms,
                                          int c16, const f4v& f0, const f4v& f1) {
    const f16v m = lds16(Ms + J * 64 + c16);
    a0 += m * qbcast<(J >> 2)>(f0[J & 3]);
    a1 += m * qbcast<(J >> 2)>(f1[J & 3]);
}
template<int... Js>
__device__ __forceinline__ void mv16_2(f16v& a0, f16v& a1, const float* Ms, int c16,
                                       const f4v& f0, const f4v& f1,
                                       std::integer_sequence<int, Js...>) {
    (mv16step2<Js>(a0, a1, Ms, c16, f0, f1), ...);
}

// Fused kernel: quad (4 lanes) per TWO rows (row q and row q+128); each lane
// owns a 16-output chunk of each. ONE phase table LDS-resident at a time
// (overlay mid-kernel): 37.12 KB -> 4 blocks/CU = 32 waves/CU, 4 independent
// 8-wave barrier domains (round 8 showed fused big domains hurt).
// Pass order caps fragment liveness (round-7-proven 64-VGPR schedule):
//   stage p1; 1. s = bv + C1 x + D12 u  [xf, uf die]
//   2. substitution s -> w
//   overlay p2 (live: s only)
//   3. acc = bx + B1 w                  [s dies]
//   4. reload x,u; acc += Ax + B2u
__global__ __launch_bounds__(BT, 4) void renl2_fused(const float* __restrict__ x,
                                                     const float* __restrict__ u,
                                                     const float* __restrict__ ws,
                                                     float* __restrict__ out) {
    __shared__ __align__(64) float sm[9280];    // 37.12 KB -> 4 blocks/CU
    const int tid = threadIdx.x;
    const int c   = tid & 3;              // quad chunk id
    const int c16 = c << 4;
    const size_t row0 = (size_t)blockIdx.x * RPB;   // rows [row0, row0+256)

    // ---- per-lane x/u fragments for both rows (fully coalesced) ----
    const f16v xf0 = *(const f16v*)(x + row0 * 64 + (size_t)tid * 16);
    const f16v xf1 = *(const f16v*)(x + (row0 + 128) * 64 + (size_t)tid * 16);
    const f4v  uf0 = *(const f4v*) (u + row0 * 16 + (size_t)tid * 4);
    const f4v  uf1 = *(const f4v*) (u + (row0 + 128) * 16 + (size_t)tid * 4);

    // ---- stage phase-1 table (2320 float4) ----
    const float4* wsv = (const float4*)ws;
    float4* smv = (float4*)sm;
#pragma unroll
    for (int i = 0; i < 4; i++) smv[tid + i * BT] = wsv[tid + i * BT];
    if (tid < 2320 - 4 * BT) smv[tid + 4 * BT] = wsv[tid + 4 * BT];
    __syncthreads();

    // ---- pass 1: s = bv + C1 x + D12 u   (xf, uf die here) ----
    f16v s0 = lds16(sm + 9216 + c16);
    f16v s1 = s0;
    mv64_2(s0, s1, sm + 0,    c16, xf0, xf1, std::make_integer_sequence<int, 64>{});
    mv16_2(s0, s1, sm + 8192, c16, uf0, uf1, std::make_integer_sequence<int, 16>{});
    fence_sched();

    // ---- pass 2: substitution (intra-quad DPP broadcast, branchless) ----
    subst_all2(s0, s1, sm + 4096, c16, c, std::make_integer_sequence<int, 64>{});
    fence_sched();

    // ---- overlay: phase-2 table (live regs: s0,s1 only) ----
    __syncthreads();
#pragma unroll
    for (int i = 0; i < 4; i++) smv[tid + i * BT] = wsv[2320 + tid + i * BT];
    if (tid < 2320 - 4 * BT) smv[tid + 4 * BT] = wsv[2320 + tid + 4 * BT];
    __syncthreads();
    // local layout now: AT@0 | B1T@4096 | B2T@8192 | bx@9216

    // ---- pass 3: acc = bx + B1 w   (s dies here) ----
    f16v acc0 = lds16(sm + 9216 + c16);
    f16v acc1 = acc0;
    mv64_2(acc0, acc1, sm + 4096, c16, s0, s1, std::make_integer_sequence<int, 64>{});
    fence_sched();

    // ---- pass 4: reload x/u (L3-hot; pointer laundered so the compiler
    //      cannot CSE-forward the pass-1 loads and resurrect their ranges),
    //      then acc += A x + B2 u ----
    size_t r0 = row0;
    asm volatile("" : "+s"(r0));          // opaque: forces a true reload
    const f16v xg0 = *(const f16v*)(x + r0 * 64 + (size_t)tid * 16);
    const f16v xg1 = *(const f16v*)(x + (r0 + 128) * 64 + (size_t)tid * 16);
    const f4v  ug0 = *(const f4v*) (u + r0 * 16 + (size_t)tid * 4);
    const f4v  ug1 = *(const f4v*) (u + (r0 + 128) * 16 + (size_t)tid * 4);
    mv64_2(acc0, acc1, sm + 0,    c16, xg0, xg1, std::make_integer_sequence<int, 64>{});
    mv16_2(acc0, acc1, sm + 8192, c16, ug0, ug1, std::make_integer_sequence<int, 16>{});

    // ---- two 64B stores: x_dot for both rows ----
    const size_t q = (size_t)(tid >> 2);
    *(f16v*)(out + (row0 + q) * 64 + c16)       = acc0;
    *(f16v*)(out + (row0 + 128 + q) * 64 + c16) = acc1;
}

extern "C" void kernel_launch(void* const* d_in, const int* in_sizes, int n_in,
                              void* d_out, int out_size, void* d_ws, size_t ws_size,
                              hipStream_t stream) {
    const float* x   = (const float*)d_in[0];
    const float* u   = (const float*)d_in[1];
    const float* A   = (const float*)d_in[2];
    const float* B1  = (const float*)d_in[3];
    const float* B2  = (const float*)d_in[4];
    const float* C1  = (const float*)d_in[5];
    const float* D11 = (const float*)d_in[6];
    const float* D12 = (const float*)d_in[7];
    const float* bv  = (const float*)d_in[8];
    const float* bx  = (const float*)d_in[9];
    float* out = (float*)d_out;
    float* ws  = (float*)d_ws;

    prep_kernel<<<16, 256, 0, stream>>>(A, B1, B2, C1, D11, D12, bv, bx, ws);
    renl2_fused<<<NROWS / RPB, BT, 0, stream>>>(x, u, ws, out);
}